// Round 1
// baseline (41.940 us; speedup 1.0000x reference)
//
#include <hip/hip_runtime.h>
#include <math.h>

// FundusQuantumLayer: 4-qubit, 3-layer variational circuit, batch 2^20.
// Factored form: ev[q] = sum_{P in {I,Z,X}^4} C[q][P] * prod_r w_{P_r}(x_r),
// w = (1, cos x, sin x). C (4x81 floats) computed on-device from weights.

#define NQ 4
#define NL 3

__global__ void fq_setup(const float* __restrict__ w, float* __restrict__ C) {
    __shared__ float Ur[16][16], Ui[16][16];   // U[k][j] : row k, column j
    __shared__ float ReM[4][16][16];           // Re(U^dag Z_q U)
    const int tid = threadIdx.x;

    if (tid < 16) {
        // simulate column `tid` of U (basis state e_tid through the shared block)
        for (int k = 0; k < 16; ++k) { Ur[k][tid] = (k == tid) ? 1.f : 0.f; Ui[k][tid] = 0.f; }
        for (int l = 0; l < NL; ++l) {
            for (int q = 0; q < NQ; ++q) {
                const int m = 1 << (3 - q);          // qubit 0 = MSB (PennyLane)
                // RY(w[l][q][0])
                {
                    float th = w[(l*NQ + q)*2 + 0];
                    float c = cosf(0.5f*th), s = sinf(0.5f*th);
                    for (int k = 0; k < 16; ++k) if (!(k & m)) {
                        float ar = Ur[k][tid],   ai = Ui[k][tid];
                        float br = Ur[k|m][tid], bi = Ui[k|m][tid];
                        Ur[k][tid]   = c*ar - s*br;  Ui[k][tid]   = c*ai - s*bi;
                        Ur[k|m][tid] = s*ar + c*br;  Ui[k|m][tid] = s*ai + c*bi;
                    }
                }
                // RZ(w[l][q][1]) = diag(e^{-i p/2}, e^{+i p/2})
                {
                    float ph = w[(l*NQ + q)*2 + 1];
                    float cp = cosf(0.5f*ph), sp = sinf(0.5f*ph);
                    for (int k = 0; k < 16; ++k) {
                        float r = Ur[k][tid], im = Ui[k][tid];
                        if (k & m) { Ur[k][tid] = r*cp - im*sp; Ui[k][tid] = im*cp + r*sp; }
                        else       { Ur[k][tid] = r*cp + im*sp; Ui[k][tid] = im*cp - r*sp; }
                    }
                }
            }
            // CNOT ring (0,1),(1,2),(2,3),(3,0)
            const int cc[4] = {0,1,2,3}, tt[4] = {1,2,3,0};
            for (int e = 0; e < 4; ++e) {
                int mc = 1 << (3 - cc[e]), mt = 1 << (3 - tt[e]);
                for (int k = 0; k < 16; ++k) {
                    if ((k & mc) && !(k & mt)) {
                        float tr = Ur[k][tid], ti = Ui[k][tid];
                        Ur[k][tid]    = Ur[k|mt][tid]; Ui[k][tid]    = Ui[k|mt][tid];
                        Ur[k|mt][tid] = tr;            Ui[k|mt][tid] = ti;
                    }
                }
            }
        }
    }
    __syncthreads();

    // ReM[q][i][j] = sum_k z_q(k) * Re(conj(U[k][i]) U[k][j]),  z_q(k)=+1 if bit(3-q)==0
    for (int idx = tid; idx < 4*16*16; idx += blockDim.x) {
        int q = idx >> 8, i = (idx >> 4) & 15, j = idx & 15;
        float sum = 0.f;
        for (int k = 0; k < 16; ++k) {
            float zq = ((k >> (3 - q)) & 1) ? -1.f : 1.f;
            sum += zq * (Ur[k][i]*Ur[k][j] + Ui[k][i]*Ui[k][j]);
        }
        ReM[q][i][j] = sum;
    }
    __syncthreads();

    // C[q][a] = tr(M_q * P_a)/16, a = ((p0*3+p1)*3+p2)*3+p3, p: 0=I 1=Z 2=X
    for (int idx = tid; idx < 4*81; idx += blockDim.x) {
        int q = idx / 81, a = idx % 81;
        int p[4] = { a/27, (a/9)%3, (a/3)%3, a%3 };
        int xm = 0, zm = 0;
        for (int r = 0; r < 4; ++r) {
            int bit = 1 << (3 - r);
            if (p[r] == 1) zm |= bit; else if (p[r] == 2) xm |= bit;
        }
        float sum = 0.f;
        for (int j = 0; j < 16; ++j) {
            float sgn = (__popc(j & zm) & 1) ? -1.f : 1.f;
            sum += sgn * ReM[q][j ^ xm][j];     // P[j][i] nonzero at i=j^xm
        }
        C[idx] = sum * (1.0f/16.0f);
    }
}

__global__ __launch_bounds__(256) void fq_main(const float4* __restrict__ x,
                                               const float* __restrict__ C,
                                               float4* __restrict__ out) {
    const int i = blockIdx.x * 256 + threadIdx.x;
    float4 xv = x[i];
    float c0 = __cosf(xv.x), s0 = __sinf(xv.x);
    float c1 = __cosf(xv.y), s1 = __sinf(xv.y);
    float c2 = __cosf(xv.z), s2 = __sinf(xv.z);
    float c3 = __cosf(xv.w), s3 = __sinf(xv.w);

    float f0[3] = {1.f, c0, s0}, f1[3] = {1.f, c1, s1};
    float f2[3] = {1.f, c2, s2}, f3[3] = {1.f, c3, s3};
    float g01[9], g23[9];
#pragma unroll
    for (int a = 0; a < 3; ++a)
#pragma unroll
        for (int b = 0; b < 3; ++b) {
            g01[a*3+b] = f0[a] * f1[b];
            g23[a*3+b] = f2[a] * f3[b];
        }

    float o[4];
#pragma unroll
    for (int q = 0; q < 4; ++q) {
        float acc = 0.f;
#pragma unroll
        for (int a = 0; a < 9; ++a) {
            float t = 0.f;
#pragma unroll
            for (int b = 0; b < 9; ++b)
                t = fmaf(C[q*81 + a*9 + b], g23[b], t);   // C uniform -> s_load/SGPR operand
            acc = fmaf(t, g01[a], acc);
        }
        o[q] = acc;
    }
    out[i] = make_float4(o[0], o[1], o[2], o[3]);
}

extern "C" void kernel_launch(void* const* d_in, const int* in_sizes, int n_in,
                              void* d_out, int out_size, void* d_ws, size_t ws_size,
                              hipStream_t stream) {
    const float* x = (const float*)d_in[0];     // [B,4] f32
    const float* w = (const float*)d_in[1];     // [3,4,2] f32
    float* C = (float*)d_ws;                    // 4*81 floats = 1296 B scratch

    fq_setup<<<1, 256, 0, stream>>>(w, C);

    const int B = in_sizes[0] / 4;              // 1048576, divisible by 256
    fq_main<<<B / 256, 256, 0, stream>>>((const float4*)x, C, (float4*)d_out);
}

// Round 2
// 33.545 us; speedup vs baseline: 1.2503x; 1.2503x over previous
//
#include <hip/hip_runtime.h>
#include <math.h>

// FundusQuantumLayer: 4-qubit, 3-layer variational circuit, batch 2^20.
// ev[q] = sum_{P in {I,Z,X}^4} C[q][P] * prod_r w_{P_r}(x_r), w = (1,cos x,sin x).
// Ct layout: float4 per Pauli string k=a*9+b (a: qubits01, b: qubits23), q in lanes.

#define NQ 4
#define NL 3
#define SPT 4   // samples per thread

__global__ void fq_setup(const float* __restrict__ w, float* __restrict__ Ct) {
    __shared__ float Ur[16][16], Ui[16][16];   // U[k][col]
    __shared__ float ReM[4][16][16];           // Re(U^dag Z_q U)
    const int tid = threadIdx.x;

    if (tid < 16) {
        // simulate column `tid` of U entirely in registers (all indices compile-time)
        float ur[16], ui[16];
#pragma unroll
        for (int k = 0; k < 16; ++k) { ur[k] = (k == tid) ? 1.f : 0.f; ui[k] = 0.f; }
#pragma unroll
        for (int l = 0; l < NL; ++l) {
#pragma unroll
            for (int q = 0; q < NQ; ++q) {
                const int m = 1 << (3 - q);          // qubit 0 = MSB (PennyLane)
                {   // RY(w[l][q][0])
                    float th = w[(l*NQ + q)*2 + 0];
                    float c = cosf(0.5f*th), s = sinf(0.5f*th);
#pragma unroll
                    for (int k = 0; k < 16; ++k) if (!(k & m)) {
                        float ar = ur[k],   ai = ui[k];
                        float br = ur[k|m], bi = ui[k|m];
                        ur[k]   = c*ar - s*br;  ui[k]   = c*ai - s*bi;
                        ur[k|m] = s*ar + c*br;  ui[k|m] = s*ai + c*bi;
                    }
                }
                {   // RZ(w[l][q][1]) = diag(e^{-i p/2}, e^{+i p/2})
                    float ph = w[(l*NQ + q)*2 + 1];
                    float cp = cosf(0.5f*ph), sp = sinf(0.5f*ph);
#pragma unroll
                    for (int k = 0; k < 16; ++k) {
                        float r = ur[k], im = ui[k];
                        if (k & m) { ur[k] = r*cp - im*sp; ui[k] = im*cp + r*sp; }
                        else       { ur[k] = r*cp + im*sp; ui[k] = im*cp - r*sp; }
                    }
                }
            }
            // CNOT ring (0,1),(1,2),(2,3),(3,0): swap |c=1,t=0> <-> |c=1,t=1>
#pragma unroll
            for (int e = 0; e < 4; ++e) {
                const int mc = 1 << (3 - e);
                const int mt = 1 << (3 - ((e + 1) & 3));
#pragma unroll
                for (int k = 0; k < 16; ++k) {
                    if ((k & mc) && !(k & mt)) {
                        float tr = ur[k], ti = ui[k];
                        ur[k]    = ur[k|mt]; ui[k]    = ui[k|mt];
                        ur[k|mt] = tr;       ui[k|mt] = ti;
                    }
                }
            }
        }
#pragma unroll
        for (int k = 0; k < 16; ++k) { Ur[k][tid] = ur[k]; Ui[k][tid] = ui[k]; }
    }
    __syncthreads();

    // ReM[q][i][j] = sum_k z_q(k) * Re(conj(U[k][i]) U[k][j])
    for (int idx = tid; idx < 4*16*16; idx += blockDim.x) {
        int q = idx >> 8, i = (idx >> 4) & 15, j = idx & 15;
        float sum = 0.f;
        for (int k = 0; k < 16; ++k) {
            float zq = ((k >> (3 - q)) & 1) ? -1.f : 1.f;
            sum += zq * (Ur[k][i]*Ur[k][j] + Ui[k][i]*Ui[k][j]);
        }
        ReM[q][i][j] = sum;
    }
    __syncthreads();

    // Ct[k*4+q] = tr(M_q * P_k)/16, k = ((p0*3+p1)*3+p2)*3+p3, p: 0=I 1=Z 2=X
    for (int idx = tid; idx < 4*81; idx += blockDim.x) {
        int q = idx / 81, k81 = idx % 81;
        int p[4] = { k81/27, (k81/9)%3, (k81/3)%3, k81%3 };
        int xm = 0, zm = 0;
        for (int r = 0; r < 4; ++r) {
            int bit = 1 << (3 - r);
            if (p[r] == 1) zm |= bit; else if (p[r] == 2) xm |= bit;
        }
        float sum = 0.f;
        for (int j = 0; j < 16; ++j) {
            float sgn = (__popc(j & zm) & 1) ? -1.f : 1.f;
            sum += sgn * ReM[q][j ^ xm][j];     // P[j][i] nonzero at i=j^xm
        }
        Ct[k81*4 + q] = sum * (1.0f/16.0f);
    }
}

__global__ __launch_bounds__(256) void fq_main(const float4* __restrict__ x,
                                               const float4* __restrict__ Ct, // [81]
                                               float4* __restrict__ out) {
    const int t0 = blockIdx.x * 256 + threadIdx.x;
    const int NT = gridDim.x * 256;            // total threads; samples strided by NT

    float g01[SPT][9], g23[SPT][9];
    float acc[SPT][4];

#pragma unroll
    for (int s = 0; s < SPT; ++s) {
        float4 xv = x[t0 + s*NT];
        float c0 = __cosf(xv.x), s0 = __sinf(xv.x);
        float c1 = __cosf(xv.y), s1 = __sinf(xv.y);
        float c2 = __cosf(xv.z), s2 = __sinf(xv.z);
        float c3 = __cosf(xv.w), s3 = __sinf(xv.w);
        float f0[3] = {1.f, c0, s0}, f1[3] = {1.f, c1, s1};
        float f2[3] = {1.f, c2, s2}, f3[3] = {1.f, c3, s3};
#pragma unroll
        for (int a = 0; a < 3; ++a)
#pragma unroll
            for (int b = 0; b < 3; ++b) {
                g01[s][a*3+b] = f0[a] * f1[b];
                g23[s][a*3+b] = f2[a] * f3[b];
            }
#pragma unroll
        for (int q = 0; q < 4; ++q) acc[s][q] = 0.f;
    }

#pragma unroll
    for (int a = 0; a < 9; ++a) {
        float t[SPT][4];
#pragma unroll
        for (int s = 0; s < SPT; ++s)
#pragma unroll
            for (int q = 0; q < 4; ++q) t[s][q] = 0.f;
#pragma unroll
        for (int b = 0; b < 9; ++b) {
            float4 c = Ct[a*9 + b];            // one dwordx4: coeffs for all 4 outputs
#pragma unroll
            for (int s = 0; s < SPT; ++s) {
                float g = g23[s][b];
                t[s][0] = fmaf(c.x, g, t[s][0]);
                t[s][1] = fmaf(c.y, g, t[s][1]);
                t[s][2] = fmaf(c.z, g, t[s][2]);
                t[s][3] = fmaf(c.w, g, t[s][3]);
            }
        }
#pragma unroll
        for (int s = 0; s < SPT; ++s) {
            float g = g01[s][a];
#pragma unroll
            for (int q = 0; q < 4; ++q)
                acc[s][q] = fmaf(t[s][q], g, acc[s][q]);
        }
    }

#pragma unroll
    for (int s = 0; s < SPT; ++s)
        out[t0 + s*NT] = make_float4(acc[s][0], acc[s][1], acc[s][2], acc[s][3]);
}

extern "C" void kernel_launch(void* const* d_in, const int* in_sizes, int n_in,
                              void* d_out, int out_size, void* d_ws, size_t ws_size,
                              hipStream_t stream) {
    const float* x = (const float*)d_in[0];     // [B,4] f32
    const float* w = (const float*)d_in[1];     // [3,4,2] f32
    float* Ct = (float*)d_ws;                   // 81 float4 = 1296 B scratch

    fq_setup<<<1, 256, 0, stream>>>(w, Ct);

    const int B = in_sizes[0] / 4;              // 1048576
    const int threads = B / SPT;                // 262144
    fq_main<<<threads / 256, 256, 0, stream>>>((const float4*)x, (const float4*)Ct,
                                               (float4*)d_out);
}

// Round 3
// 31.795 us; speedup vs baseline: 1.3191x; 1.0550x over previous
//
#include <hip/hip_runtime.h>
#include <math.h>

// FundusQuantumLayer: 4-qubit, 3-layer variational circuit, batch 2^20.
// ev[q] = sum_{P in {I,Z,X}^4} C[q][P] * prod_r w_{P_r}(x_r), w = (1,cos x,sin x).
// Ct layout: float4 per Pauli string k=a*9+b (a: qubits01, b: qubits23), q in .xyzw.

#define NQ 4
#define NL 3
#define SPT 4   // samples per thread

__global__ void fq_setup(const float* __restrict__ w, float* __restrict__ Ct) {
    __shared__ float Ur[16][16], Ui[16][16];   // U[k][col]
    __shared__ float ReM[4][16][16];           // Re(U^dag Z_q U)
    const int tid = threadIdx.x;

    if (tid < 16) {
        // simulate column `tid` of U entirely in registers (all indices compile-time)
        float ur[16], ui[16];
#pragma unroll
        for (int k = 0; k < 16; ++k) { ur[k] = (k == tid) ? 1.f : 0.f; ui[k] = 0.f; }
#pragma unroll
        for (int l = 0; l < NL; ++l) {
#pragma unroll
            for (int q = 0; q < NQ; ++q) {
                const int m = 1 << (3 - q);          // qubit 0 = MSB (PennyLane)
                {   // RY(w[l][q][0])
                    float th = w[(l*NQ + q)*2 + 0];
                    float c = __cosf(0.5f*th), s = __sinf(0.5f*th);
#pragma unroll
                    for (int k = 0; k < 16; ++k) if (!(k & m)) {
                        float ar = ur[k],   ai = ui[k];
                        float br = ur[k|m], bi = ui[k|m];
                        ur[k]   = c*ar - s*br;  ui[k]   = c*ai - s*bi;
                        ur[k|m] = s*ar + c*br;  ui[k|m] = s*ai + c*bi;
                    }
                }
                {   // RZ(w[l][q][1]) = diag(e^{-i p/2}, e^{+i p/2})
                    float ph = w[(l*NQ + q)*2 + 1];
                    float cp = __cosf(0.5f*ph), sp = __sinf(0.5f*ph);
#pragma unroll
                    for (int k = 0; k < 16; ++k) {
                        float r = ur[k], im = ui[k];
                        if (k & m) { ur[k] = r*cp - im*sp; ui[k] = im*cp + r*sp; }
                        else       { ur[k] = r*cp + im*sp; ui[k] = im*cp - r*sp; }
                    }
                }
            }
            // CNOT ring (0,1),(1,2),(2,3),(3,0): swap |c=1,t=0> <-> |c=1,t=1>
#pragma unroll
            for (int e = 0; e < 4; ++e) {
                const int mc = 1 << (3 - e);
                const int mt = 1 << (3 - ((e + 1) & 3));
#pragma unroll
                for (int k = 0; k < 16; ++k) {
                    if ((k & mc) && !(k & mt)) {
                        float tr = ur[k], ti = ui[k];
                        ur[k]    = ur[k|mt]; ui[k]    = ui[k|mt];
                        ur[k|mt] = tr;       ui[k|mt] = ti;
                    }
                }
            }
        }
#pragma unroll
        for (int k = 0; k < 16; ++k) { Ur[k][tid] = ur[k]; Ui[k][tid] = ui[k]; }
    }
    __syncthreads();

    // ReM[q][i][j] = sum_k z_q(k) * Re(conj(U[k][i]) U[k][j])
    for (int idx = tid; idx < 4*16*16; idx += blockDim.x) {
        int q = idx >> 8, i = (idx >> 4) & 15, j = idx & 15;
        float sum = 0.f;
        for (int k = 0; k < 16; ++k) {
            float zq = ((k >> (3 - q)) & 1) ? -1.f : 1.f;
            sum += zq * (Ur[k][i]*Ur[k][j] + Ui[k][i]*Ui[k][j]);
        }
        ReM[q][i][j] = sum;
    }
    __syncthreads();

    // Ct[k*4+q] = tr(M_q * P_k)/16, k = ((p0*3+p1)*3+p2)*3+p3, p: 0=I 1=Z 2=X
    for (int idx = tid; idx < 4*81; idx += blockDim.x) {
        int q = idx / 81, k81 = idx % 81;
        int p[4] = { k81/27, (k81/9)%3, (k81/3)%3, k81%3 };
        int xm = 0, zm = 0;
        for (int r = 0; r < 4; ++r) {
            int bit = 1 << (3 - r);
            if (p[r] == 1) zm |= bit; else if (p[r] == 2) xm |= bit;
        }
        float sum = 0.f;
        for (int j = 0; j < 16; ++j) {
            float sgn = (__popc(j & zm) & 1) ? -1.f : 1.f;
            sum += sgn * ReM[q][j ^ xm][j];     // P[j][i] nonzero at i=j^xm
        }
        Ct[k81*4 + q] = sum * (1.0f/16.0f);
    }
}

__global__ __launch_bounds__(256) void fq_main(const float4* __restrict__ x,
                                               const float4* __restrict__ Ct, // [81]
                                               float4* __restrict__ out) {
    __shared__ float4 sCt[81];
    const int tid = threadIdx.x;
    if (tid < 81) sCt[tid] = Ct[tid];          // 1296 B/block, one pass
    __syncthreads();

    const int t0 = blockIdx.x * 256 + tid;
    const int NT = gridDim.x * 256;            // samples strided by NT

    float g01[SPT][9], g23[SPT][9];
    float acc[SPT][4];

#pragma unroll
    for (int s = 0; s < SPT; ++s) {
        float4 xv = x[t0 + s*NT];
        float c0 = __cosf(xv.x), s0 = __sinf(xv.x);
        float c1 = __cosf(xv.y), s1 = __sinf(xv.y);
        float c2 = __cosf(xv.z), s2 = __sinf(xv.z);
        float c3 = __cosf(xv.w), s3 = __sinf(xv.w);
        float f0[3] = {1.f, c0, s0}, f1[3] = {1.f, c1, s1};
        float f2[3] = {1.f, c2, s2}, f3[3] = {1.f, c3, s3};
#pragma unroll
        for (int a = 0; a < 3; ++a)
#pragma unroll
            for (int b = 0; b < 3; ++b) {
                g01[s][a*3+b] = f0[a] * f1[b];
                g23[s][a*3+b] = f2[a] * f3[b];
            }
#pragma unroll
        for (int q = 0; q < 4; ++q) acc[s][q] = 0.f;
    }

#pragma unroll
    for (int a = 0; a < 9; ++a) {
        float t[SPT][4];
#pragma unroll
        for (int s = 0; s < SPT; ++s)
#pragma unroll
            for (int q = 0; q < 4; ++q) t[s][q] = 0.f;
#pragma unroll
        for (int b = 0; b < 9; ++b) {
            float4 c = sCt[a*9 + b];           // ds_read_b128, same addr = broadcast
#pragma unroll
            for (int s = 0; s < SPT; ++s) {
                float g = g23[s][b];
                t[s][0] = fmaf(c.x, g, t[s][0]);
                t[s][1] = fmaf(c.y, g, t[s][1]);
                t[s][2] = fmaf(c.z, g, t[s][2]);
                t[s][3] = fmaf(c.w, g, t[s][3]);
            }
        }
#pragma unroll
        for (int s = 0; s < SPT; ++s) {
            float g = g01[s][a];
#pragma unroll
            for (int q = 0; q < 4; ++q)
                acc[s][q] = fmaf(t[s][q], g, acc[s][q]);
        }
        // Keep at most this iteration's 9 float4 coefficient loads live:
        // block the scheduler from hoisting next iteration's ds_reads up.
        __builtin_amdgcn_sched_barrier(0);
    }

#pragma unroll
    for (int s = 0; s < SPT; ++s)
        out[t0 + s*NT] = make_float4(acc[s][0], acc[s][1], acc[s][2], acc[s][3]);
}

extern "C" void kernel_launch(void* const* d_in, const int* in_sizes, int n_in,
                              void* d_out, int out_size, void* d_ws, size_t ws_size,
                              hipStream_t stream) {
    const float* x = (const float*)d_in[0];     // [B,4] f32
    const float* w = (const float*)d_in[1];     // [3,4,2] f32
    float* Ct = (float*)d_ws;                   // 81 float4 = 1296 B scratch

    fq_setup<<<1, 256, 0, stream>>>(w, Ct);

    const int B = in_sizes[0] / 4;              // 1048576
    const int threads = B / SPT;                // 262144
    fq_main<<<threads / 256, 256, 0, stream>>>((const float4*)x, (const float4*)Ct,
                                               (float4*)d_out);
}